// Round 2
// baseline (837.277 us; speedup 1.0000x reference)
//
#include <hip/hip_runtime.h>

#define HH   512
#define WW   512
#define CIN  16
#define COUT 16
#define HW   (HH * WW)

// Thread: one (n,h) row, 4 pixels (w, w+64, w+128, w+192), all 16 out-channels.
// Block (64,4) -> tile 256 wide x 4 tall. Grid (2,128,16).
//
// Key structure: the 20 (tap d x pixel p) byte offsets and validity masks are
// computed ONCE per thread (loop-invariant in input channel i). Loads become
// global_load_dword v, v_off, s[chan_base] with no per-load VALU addressing;
// zero-padding is one v_cndmask with an sgpr-pair lane mask.
__global__ __launch_bounds__(256, 4) void diag_conv_kernel(
    const float* __restrict__ x, const float* __restrict__ fw,
    float* __restrict__ out)
{
    const int tx    = threadIdx.x;               // 0..63
    const int ty    = threadIdx.y;               // 0..3
    const int n     = blockIdx.z;
    const int h     = blockIdx.y * 4 + ty;
    const int wbase = blockIdx.x * 256 + tx;

    // ---- hoisted per-thread offsets + validity (invariant in i) ----
    int  boff[5][4];
    bool ok[5][4];
#pragma unroll
    for (int d = 0; d < 5; ++d) {
        const int  hh  = h + d - 2;
        const bool hok = (unsigned)hh < (unsigned)HH;
        const int  hcl = hok ? hh : 0;                   // memory-safe row
#pragma unroll
        for (int p = 0; p < 4; ++p) {
            const int  ww  = wbase + p * 64 + d - 2;
            const bool wok = (unsigned)ww < (unsigned)WW;
            const int  wcl = wok ? ww : 0;               // memory-safe col
            boff[d][p] = (hcl * WW + wcl) * 4;           // byte offset in channel
            ok[d][p]   = hok && wok;
        }
    }

    float acc[COUT][4];
#pragma unroll
    for (int o = 0; o < COUT; ++o)
#pragma unroll
        for (int p = 0; p < 4; ++p) acc[o][p] = 0.f;

    const char* xn = (const char*)(x + (size_t)n * CIN * HW);

#pragma unroll 4
    for (int i = 0; i < CIN; ++i) {
        const char* xi = xn + (size_t)i * (HW * 4);      // block-uniform -> SGPR base
#pragma unroll
        for (int d = 0; d < 5; ++d) {
            float v[4];
#pragma unroll
            for (int p = 0; p < 4; ++p) {
                const float t = *(const float*)(xi + boff[d][p]);
                v[p] = ok[d][p] ? t : 0.f;               // 1 cndmask (sgpr-pair mask)
            }
#pragma unroll
            for (int o = 0; o < COUT; ++o) {
                const float wt = fw[(o * CIN + i) * 5 + d];  // uniform -> s_load
#pragma unroll
                for (int p = 0; p < 4; ++p)
                    acc[o][p] = fmaf(wt, v[p], acc[o][p]);
            }
        }
    }

    float* on = out + (size_t)n * COUT * HW + (size_t)h * WW + wbase;
#pragma unroll
    for (int o = 0; o < COUT; ++o) {
#pragma unroll
        for (int p = 0; p < 4; ++p)
            on[(size_t)o * HW + p * 64] = acc[o][p];
    }
}

extern "C" void kernel_launch(void* const* d_in, const int* in_sizes, int n_in,
                              void* d_out, int out_size, void* d_ws, size_t ws_size,
                              hipStream_t stream) {
    const float* x  = (const float*)d_in[0];   // [16,16,512,512] fp32
    const float* fw = (const float*)d_in[1];   // [16,16,5]       fp32
    float* out = (float*)d_out;                // [16,16,512,512] fp32

    dim3 block(64, 4, 1);
    dim3 grid(WW / 256, HH / 4, 16);
    hipLaunchKernelGGL(diag_conv_kernel, grid, block, 0, stream, x, fw, out);
}